// Round 10
// baseline (828.801 us; speedup 1.0000x reference)
//
#include <hip/hip_runtime.h>
#include <stdint.h>

typedef __attribute__((ext_vector_type(8))) short v8s;
typedef __attribute__((ext_vector_type(4))) float v4f;

#define NBATCH 32
#define SEQ 2048
#define DHEAD 64

__device__ __forceinline__ unsigned short f2bf(float f) {
  unsigned int x = __float_as_uint(f);
  x += 0x7fffu + ((x >> 16) & 1u);
  return (unsigned short)(x >> 16);
}

__device__ __forceinline__ float bf2f(short s) {
  return __uint_as_float(((unsigned int)(unsigned short)s) << 16);
}

// ---- prepass: fp32 -> bf16 copy, Q and K in one launch (blockIdx.y picks) ----
// Q is PRE-SCALED by 0.125*log2(e) so phase 1's exp2 needs no multiply:
// exp(S/8) = exp2(S * 0.125*log2e) = exp2( (Q*0.18033688) . K ).
__global__ void cvt_bf16_qk_k(const float* __restrict__ Q, const float* __restrict__ K,
                              unsigned short* __restrict__ Qb,
                              unsigned short* __restrict__ Kb, int n4) {
  int i = blockIdx.x * blockDim.x + threadIdx.x;
  if (i >= n4) return;
  const float* src = blockIdx.y ? K : Q;
  unsigned short* dst = blockIdx.y ? Kb : Qb;
  const float sc = blockIdx.y ? 1.0f : 0.18033688f;
  float4 v = ((const float4*)src)[i];
  ushort4 o;
  o.x = f2bf(v.x * sc); o.y = f2bf(v.y * sc);
  o.z = f2bf(v.z * sc); o.w = f2bf(v.w * sc);
  ((ushort4*)dst)[i] = o;
}

// ---- prepass: V (n,k,d) -> Vt (n,d,k) bf16 ----
__global__ void vtrans_k(const float* __restrict__ V,
                         unsigned short* __restrict__ Vt) {
  __shared__ float tile[64][65];
  int n = blockIdx.y, k0 = blockIdx.x * 64;
  int t = threadIdx.x;
  int c = t & 63, rb = t >> 6;
#pragma unroll
  for (int it = 0; it < 16; ++it) {
    int r = it * 4 + rb;
    tile[r][c] = V[((size_t)(n * SEQ + k0 + r)) * DHEAD + c];
  }
  __syncthreads();
#pragma unroll
  for (int it = 0; it < 16; ++it) {
    int d = it * 4 + rb;
    Vt[((size_t)(n * DHEAD + d)) * SEQ + k0 + c] = f2bf(tile[c][d]);
  }
}

// ---- prepass: attn_mask (m,k) int -> bits along k: amB[m][k/32] ----
__global__ void pack_amB_k(const int* __restrict__ am, unsigned int* __restrict__ amB) {
  int tid = blockIdx.x * blockDim.x + threadIdx.x;  // SEQ*64 = 131072 threads
  int w = tid & 63, m = tid >> 6;
  unsigned int bits = 0;
#pragma unroll 4
  for (int i = 0; i < 32; ++i)
    bits |= (am[(size_t)m * SEQ + w * 32 + i] != 0 ? 1u : 0u) << i;
  amB[m * 64 + w] = bits;
}

// ---- prepass: key_padding_mask (n,k) int -> bits kpmB[n][k/32] ----
__global__ void pack_kpm_k(const int* __restrict__ kpm, unsigned int* __restrict__ kpmB) {
  int tid = blockIdx.x * blockDim.x + threadIdx.x;  // 2048 threads
  if (tid >= NBATCH * 64) return;
  int n = tid >> 6, w = tid & 63;
  unsigned int bits = 0;
#pragma unroll 4
  for (int i = 0; i < 32; ++i)
    bits |= (kpm[n * SEQ + w * 32 + i] != 0 ? 1u : 0u) << i;
  kpmB[n * 64 + w] = bits;
}

// ---- main fused attention kernel ----
// 1D grid of 4096 blocks, XCD-SWIZZLED: hardware round-robins linear wg id
// across the 8 XCDs, so we map wg -> (n, row-block) such that all 128
// row-blocks of batch n execute on XCD n&7. Then K(n)+Vt(n) (512 KiB; 4
// batches -> 2 MiB) stays resident in that XCD's 4 MiB L2 instead of 2 GiB
// of re-reads hitting Infinity Cache. Bijection: b=(xcd,slot); slot=(nIdx,
// rowblk); n=xcd+8*nIdx.
//
// block = 512 threads (8 waves). Each block: one batch n, 16 query rows.
// Wave w owns key columns [256w, 256w+256).
// Phase 1 computes S^T via mfma(Kfrag, Qfrag): C col=lane&15 = QUERY row,
// C row = quad*4+r = 4 CONSECUTIVE key cols per lane -> one ds_write_b64 of
// packed bf16 per kt, scalar row-sum per lane, one OR'd mask word per 2 kt.
// P stored UNNORMALIZED; 1/rowsum folded into outW read-out and O epilogue.
// outW stores NON-TEMPORAL, issued before PV MFMA so drain hides under it.
__global__ __launch_bounds__(512, 4)
void attn_main_k(const unsigned short* __restrict__ Qb,
                 const unsigned short* __restrict__ Kb,
                 const unsigned short* __restrict__ Vt,
                 const unsigned int* __restrict__ amB,
                 const unsigned int* __restrict__ kpmB,
                 float* __restrict__ outO, float* __restrict__ outW) {
  // [0,65536): P bf16, 16 rows x 4096 B, XOR-swizzled
  //   byte = row*4096 + ((col/8 ^ (row&7))*16) + (col&7)*2
  // [65536,66048): wsum[8][16] cross-wave row sums
  __shared__ __align__(16) char smem[66048];

  // XCD-aware swizzle (bijective on 0..4095)
  const int b = blockIdx.x;
  const int xcd = b & 7, slot = b >> 3;      // 8 XCDs x 512 slots
  const int n = xcd + ((slot >> 7) << 3);    // batches {xcd, xcd+8, xcd+16, xcd+24}
  const int row0 = (slot & 127) * 16;

  const int tid = threadIdx.x;
  const int wave = tid >> 6, lane = tid & 63;
  const int quad = lane >> 4, lq = lane & 15;
  const int colw = wave * 256;

  // Q B-fragments: Q[row0+lq][quad*8 + j] (+32 for second MFMA)
  const unsigned short* qp = Qb + ((size_t)(n * SEQ + row0 + lq)) * DHEAD + quad * 8;
  v8s a0 = *(const v8s*)qp;
  v8s a1 = *(const v8s*)(qp + 32);

  float rsum = 0.f;
  const unsigned int* amRow = amB + (size_t)(row0 + lq) * 64;
  const unsigned int* kpmRow = kpmB + n * 64 + (colw >> 5);

  // ---- Phase 1: S^T = (QK^T)^T, mask, exp -> unnormalized bf16 P to LDS
#pragma unroll
  for (int kt = 0; kt < 16; ++kt) {
    const int col = colw + kt * 16 + lq;  // K row for A-fragment
    const unsigned short* kp = Kb + ((size_t)(n * SEQ + col)) * DHEAD + quad * 8;
    v8s b0 = *(const v8s*)kp;
    v8s b1 = *(const v8s*)(kp + 32);
    v4f c = {0.f, 0.f, 0.f, 0.f};
    c = __builtin_amdgcn_mfma_f32_16x16x32_bf16(b0, a0, c, 0, 0, 0);  // A=K, B=Q
    c = __builtin_amdgcn_mfma_f32_16x16x32_bf16(b1, a1, c, 0, 0, 0);
    // one mask word covers key cols [colw + (kt>>1)*32, +32):
    unsigned int mw = amRow[(colw >> 5) + (kt >> 1)] | kpmRow[kt >> 1];
    const int bitbase = (kt & 1) * 16 + quad * 4;
    float e0, e1, e2, e3;
    e0 = (mw >> (bitbase + 0)) & 1u ? 0.f : exp2f(c[0]);
    e1 = (mw >> (bitbase + 1)) & 1u ? 0.f : exp2f(c[1]);
    e2 = (mw >> (bitbase + 2)) & 1u ? 0.f : exp2f(c[2]);
    e3 = (mw >> (bitbase + 3)) & 1u ? 0.f : exp2f(c[3]);
    rsum += (e0 + e1) + (e2 + e3);
    // pack 4 bf16 (4 consecutive key cols at row lq) -> one 8B LDS write
    uint2 dd;
    dd.x = ((unsigned int)f2bf(e0)) | (((unsigned int)f2bf(e1)) << 16);
    dd.y = ((unsigned int)f2bf(e2)) | (((unsigned int)f2bf(e3)) << 16);
    const int col0 = colw + kt * 16 + quad * 4;
    *(uint2*)(smem + lq * 4096 +
              ((((col0 >> 3) ^ (lq & 7)) << 4) | ((quad & 1) << 3))) = dd;
  }

  // ---- Row-sum reduce: all of lane's values belong to row lq -> quad reduce
  rsum += __shfl_xor(rsum, 16);
  rsum += __shfl_xor(rsum, 32);
  float* wsum = (float*)(smem + 65536);  // [8 waves][16 rows]
  if (quad == 0) wsum[wave * 16 + lq] = rsum;
  __syncthreads();  // P fully written + wsum visible

  // 1/rowsum for the rows this lane's PV accumulators own (quad*4+r)
  float rinv[4];
#pragma unroll
  for (int r = 0; r < 4; ++r) {
    float s = 0.f;
#pragma unroll
    for (int w = 0; w < 8; ++w) s += wsum[w * 16 + quad * 4 + r];
    rinv[r] = 1.0f / s;
  }

  // ---- Phase 2b: coalesced vectorized outW write from LDS, x (1/rowsum).
  // Issued BEFORE the PV MFMA so store drain overlaps compute.
  // Wave w owns rows {2w, 2w+1}; each pass one wave writes 2048B contiguous.
  {
    float s0 = 0.f, s1 = 0.f;
#pragma unroll
    for (int w = 0; w < 8; ++w) {
      s0 += wsum[w * 16 + wave * 2];
      s1 += wsum[w * 16 + wave * 2 + 1];
    }
    const float rw0 = 1.0f / s0, rw1 = 1.0f / s1;
    float* wbase = outW + ((size_t)(n * SEQ + row0)) * SEQ;
#pragma unroll
    for (int ps = 0; ps < 8; ++ps) {
      const int row = wave * 2 + (ps & 1);
      const float rs = (ps & 1) ? rw1 : rw0;
      const int cb8 = lane + ((ps >> 1) << 6);  // 16B-block index 0..255
      v8s pv = *(const v8s*)(smem + row * 4096 + ((cb8 ^ (row & 7)) << 4));
      v4f f0, f1;
      f0.x = bf2f(pv[0]) * rs; f0.y = bf2f(pv[1]) * rs;
      f0.z = bf2f(pv[2]) * rs; f0.w = bf2f(pv[3]) * rs;
      f1.x = bf2f(pv[4]) * rs; f1.y = bf2f(pv[5]) * rs;
      f1.z = bf2f(pv[6]) * rs; f1.w = bf2f(pv[7]) * rs;
      v4f* dst = (v4f*)(wbase + (size_t)row * SEQ + (cb8 << 3));
      __builtin_nontemporal_store(f0, dst);
      __builtin_nontemporal_store(f1, dst + 1);
    }
  }

  // ---- Phase 3: O_partial = P(16x256) x V(256x64) via MFMA (LDS reads)
  v4f acc[4] = {{0.f,0.f,0.f,0.f},{0.f,0.f,0.f,0.f},{0.f,0.f,0.f,0.f},{0.f,0.f,0.f,0.f}};
#pragma unroll
  for (int ch = 0; ch < 8; ++ch) {
    const int cb = colw + ch * 32;
    v8s ap = *(const v8s*)(smem + lq * 4096 + (((((cb >> 3) + quad) ^ (lq & 7)) << 4)));
#pragma unroll
    for (int dt = 0; dt < 4; ++dt) {
      const unsigned short* vp =
          Vt + ((size_t)(n * DHEAD + dt * 16 + lq)) * SEQ + cb + quad * 8;
      v8s bp = *(const v8s*)vp;
      acc[dt] = __builtin_amdgcn_mfma_f32_16x16x32_bf16(ap, bp, acc[dt], 0, 0, 0);
    }
  }
  __syncthreads();  // all P reads (phase 2b + 3) done before olds overwrites

  // ---- Phase 4: cross-wave O reduction (8 partials of 16x64) through LDS;
  // rinv folded in before the store (per-row constant, distributes over sum).
  float* olds = (float*)smem;  // [8][16][68] padded
#pragma unroll
  for (int dt = 0; dt < 4; ++dt)
#pragma unroll
    for (int r = 0; r < 4; ++r)
      olds[wave * 1088 + (quad * 4 + r) * 68 + dt * 16 + lq] = acc[dt][r] * rinv[r];
  __syncthreads();
#pragma unroll
  for (int s = 0; s < 2; ++s) {
    int e = tid + s * 512;
    int row = e >> 6, d = e & 63;
    float a = 0.f;
#pragma unroll
    for (int w = 0; w < 8; ++w) a += olds[w * 1088 + row * 68 + d];
    __builtin_nontemporal_store(
        a, outO + ((size_t)(n * SEQ + row0 + row)) * DHEAD + d);
  }
}

extern "C" void kernel_launch(void* const* d_in, const int* in_sizes, int n_in,
                              void* d_out, int out_size, void* d_ws, size_t ws_size,
                              hipStream_t stream) {
  const float* Q = (const float*)d_in[0];
  const float* K = (const float*)d_in[1];
  const float* V = (const float*)d_in[2];
  const int* kpm = (const int*)d_in[3];
  const int* am = (const int*)d_in[4];

  float* outO = (float*)d_out;
  float* outW = outO + (size_t)NBATCH * SEQ * DHEAD;  // 4,194,304 floats

  char* ws = (char*)d_ws;
  unsigned short* Qb = (unsigned short*)ws;                       // 8 MiB
  unsigned short* Kb = (unsigned short*)(ws + (8u << 20));        // 8 MiB
  unsigned short* Vt = (unsigned short*)(ws + (16u << 20));       // 8 MiB
  unsigned int* amB = (unsigned int*)(ws + (24u << 20));          // 512 KiB
  unsigned int* kpmB = (unsigned int*)(ws + (24u << 20) + (1u << 19));  // 8 KiB

  const int n4 = NBATCH * SEQ * DHEAD / 4;  // 1,048,576
  cvt_bf16_qk_k<<<dim3(n4 / 256, 2), 256, 0, stream>>>(Q, K, Qb, Kb, n4);
  vtrans_k<<<dim3(SEQ / 64, NBATCH), 256, 0, stream>>>(V, Vt);
  pack_amB_k<<<(SEQ * 64) / 256, 256, 0, stream>>>(am, amB);
  pack_kpm_k<<<8, 256, 0, stream>>>(kpm, kpmB);
  attn_main_k<<<NBATCH * (SEQ / 16), 512, 0, stream>>>(Qb, Kb, Vt, amB, kpmB,
                                                       outO, outW);
}

// Round 11
// 817.532 us; speedup vs baseline: 1.0138x; 1.0138x over previous
//
#include <hip/hip_runtime.h>
#include <stdint.h>

typedef __attribute__((ext_vector_type(8))) short v8s;
typedef __attribute__((ext_vector_type(4))) float v4f;

#define NBATCH 32
#define SEQ 2048
#define DHEAD 64

__device__ __forceinline__ unsigned short f2bf(float f) {
  unsigned int x = __float_as_uint(f);
  x += 0x7fffu + ((x >> 16) & 1u);
  return (unsigned short)(x >> 16);
}

__device__ __forceinline__ float bf2f(short s) {
  return __uint_as_float(((unsigned int)(unsigned short)s) << 16);
}

// ---- prepass: fp32 -> bf16 copy, Q and K in one launch (blockIdx.y picks) ----
// Q is PRE-SCALED by 0.125*log2(e) so phase 1's exp2 needs no multiply:
// exp(S/8) = exp2(S * 0.125*log2e) = exp2( (Q*0.18033688) . K ).
__global__ void cvt_bf16_qk_k(const float* __restrict__ Q, const float* __restrict__ K,
                              unsigned short* __restrict__ Qb,
                              unsigned short* __restrict__ Kb, int n4) {
  int i = blockIdx.x * blockDim.x + threadIdx.x;
  if (i >= n4) return;
  const float* src = blockIdx.y ? K : Q;
  unsigned short* dst = blockIdx.y ? Kb : Qb;
  const float sc = blockIdx.y ? 1.0f : 0.18033688f;
  float4 v = ((const float4*)src)[i];
  ushort4 o;
  o.x = f2bf(v.x * sc); o.y = f2bf(v.y * sc);
  o.z = f2bf(v.z * sc); o.w = f2bf(v.w * sc);
  ((ushort4*)dst)[i] = o;
}

// ---- prepass: V (n,k,d) -> Vt (n,d,k) bf16 ----
__global__ void vtrans_k(const float* __restrict__ V,
                         unsigned short* __restrict__ Vt) {
  __shared__ float tile[64][65];
  int n = blockIdx.y, k0 = blockIdx.x * 64;
  int t = threadIdx.x;
  int c = t & 63, rb = t >> 6;
#pragma unroll
  for (int it = 0; it < 16; ++it) {
    int r = it * 4 + rb;
    tile[r][c] = V[((size_t)(n * SEQ + k0 + r)) * DHEAD + c];
  }
  __syncthreads();
#pragma unroll
  for (int it = 0; it < 16; ++it) {
    int d = it * 4 + rb;
    Vt[((size_t)(n * DHEAD + d)) * SEQ + k0 + c] = f2bf(tile[c][d]);
  }
}

// ---- prepass: attn_mask (m,k) int -> bits along k: amB[m][k/32] ----
__global__ void pack_amB_k(const int* __restrict__ am, unsigned int* __restrict__ amB) {
  int tid = blockIdx.x * blockDim.x + threadIdx.x;  // SEQ*64 = 131072 threads
  int w = tid & 63, m = tid >> 6;
  unsigned int bits = 0;
#pragma unroll 4
  for (int i = 0; i < 32; ++i)
    bits |= (am[(size_t)m * SEQ + w * 32 + i] != 0 ? 1u : 0u) << i;
  amB[m * 64 + w] = bits;
}

// ---- prepass: key_padding_mask (n,k) int -> bits kpmB[n][k/32] ----
__global__ void pack_kpm_k(const int* __restrict__ kpm, unsigned int* __restrict__ kpmB) {
  int tid = blockIdx.x * blockDim.x + threadIdx.x;  // 2048 threads
  if (tid >= NBATCH * 64) return;
  int n = tid >> 6, w = tid & 63;
  unsigned int bits = 0;
#pragma unroll 4
  for (int i = 0; i < 32; ++i)
    bits |= (kpm[n * SEQ + w * 32 + i] != 0 ? 1u : 0u) << i;
  kpmB[n * 64 + w] = bits;
}

// ---- main fused attention kernel ----
// 1D grid of 4096 blocks, XCD-swizzled (neutral per R10 counters, but free).
// block = 512 threads (8 waves). Each block: one batch n, 16 query rows.
// Wave w owns key columns [256w, 256w+256).
// Phase 1 computes S^T via mfma(Kfrag, Qfrag): C col=lane&15 = QUERY row,
// C row = quad*4+r = 4 CONSECUTIVE key cols per lane -> one ds_write_b64 of
// packed bf16 per kt, scalar row-sum per lane, one OR'd mask word per 2 kt.
// P stored UNNORMALIZED; 1/rowsum folded into outW read-out and O epilogue.
// outW stores are PLAIN (R10 counters: nontemporal stores caused 1.74x write
// amplification, 963 vs 554 MB, and capped streaming at ~2.8 TB/s; the
// harness fill proves plain stores hit 6.24 TB/s). Stores still issue
// BEFORE the PV MFMA so the L2 writeback drains under compute.
__global__ __launch_bounds__(512, 4)
void attn_main_k(const unsigned short* __restrict__ Qb,
                 const unsigned short* __restrict__ Kb,
                 const unsigned short* __restrict__ Vt,
                 const unsigned int* __restrict__ amB,
                 const unsigned int* __restrict__ kpmB,
                 float* __restrict__ outO, float* __restrict__ outW) {
  // [0,65536): P bf16, 16 rows x 4096 B, XOR-swizzled
  //   byte = row*4096 + ((col/8 ^ (row&7))*16) + (col&7)*2
  // [65536,66048): wsum[8][16] cross-wave row sums
  __shared__ __align__(16) char smem[66048];

  // XCD-aware swizzle (bijective on 0..4095)
  const int b = blockIdx.x;
  const int xcd = b & 7, slot = b >> 3;      // 8 XCDs x 512 slots
  const int n = xcd + ((slot >> 7) << 3);    // batches {xcd, xcd+8, xcd+16, xcd+24}
  const int row0 = (slot & 127) * 16;

  const int tid = threadIdx.x;
  const int wave = tid >> 6, lane = tid & 63;
  const int quad = lane >> 4, lq = lane & 15;
  const int colw = wave * 256;

  // Q B-fragments: Q[row0+lq][quad*8 + j] (+32 for second MFMA)
  const unsigned short* qp = Qb + ((size_t)(n * SEQ + row0 + lq)) * DHEAD + quad * 8;
  v8s a0 = *(const v8s*)qp;
  v8s a1 = *(const v8s*)(qp + 32);

  float rsum = 0.f;
  const unsigned int* amRow = amB + (size_t)(row0 + lq) * 64;
  const unsigned int* kpmRow = kpmB + n * 64 + (colw >> 5);

  // ---- Phase 1: S^T = (QK^T)^T, mask, exp -> unnormalized bf16 P to LDS
#pragma unroll
  for (int kt = 0; kt < 16; ++kt) {
    const int col = colw + kt * 16 + lq;  // K row for A-fragment
    const unsigned short* kp = Kb + ((size_t)(n * SEQ + col)) * DHEAD + quad * 8;
    v8s b0 = *(const v8s*)kp;
    v8s b1 = *(const v8s*)(kp + 32);
    v4f c = {0.f, 0.f, 0.f, 0.f};
    c = __builtin_amdgcn_mfma_f32_16x16x32_bf16(b0, a0, c, 0, 0, 0);  // A=K, B=Q
    c = __builtin_amdgcn_mfma_f32_16x16x32_bf16(b1, a1, c, 0, 0, 0);
    // one mask word covers key cols [colw + (kt>>1)*32, +32):
    unsigned int mw = amRow[(colw >> 5) + (kt >> 1)] | kpmRow[kt >> 1];
    const int bitbase = (kt & 1) * 16 + quad * 4;
    float e0, e1, e2, e3;
    e0 = (mw >> (bitbase + 0)) & 1u ? 0.f : exp2f(c[0]);
    e1 = (mw >> (bitbase + 1)) & 1u ? 0.f : exp2f(c[1]);
    e2 = (mw >> (bitbase + 2)) & 1u ? 0.f : exp2f(c[2]);
    e3 = (mw >> (bitbase + 3)) & 1u ? 0.f : exp2f(c[3]);
    rsum += (e0 + e1) + (e2 + e3);
    // pack 4 bf16 (4 consecutive key cols at row lq) -> one 8B LDS write
    uint2 dd;
    dd.x = ((unsigned int)f2bf(e0)) | (((unsigned int)f2bf(e1)) << 16);
    dd.y = ((unsigned int)f2bf(e2)) | (((unsigned int)f2bf(e3)) << 16);
    const int col0 = colw + kt * 16 + quad * 4;
    *(uint2*)(smem + lq * 4096 +
              ((((col0 >> 3) ^ (lq & 7)) << 4) | ((quad & 1) << 3))) = dd;
  }

  // ---- Row-sum reduce: all of lane's values belong to row lq -> quad reduce
  rsum += __shfl_xor(rsum, 16);
  rsum += __shfl_xor(rsum, 32);
  float* wsum = (float*)(smem + 65536);  // [8 waves][16 rows]
  if (quad == 0) wsum[wave * 16 + lq] = rsum;
  __syncthreads();  // P fully written + wsum visible

  // 1/rowsum for the rows this lane's PV accumulators own (quad*4+r)
  float rinv[4];
#pragma unroll
  for (int r = 0; r < 4; ++r) {
    float s = 0.f;
#pragma unroll
    for (int w = 0; w < 8; ++w) s += wsum[w * 16 + quad * 4 + r];
    rinv[r] = 1.0f / s;
  }

  // ---- Phase 2b: coalesced vectorized outW write from LDS, x (1/rowsum).
  // Issued BEFORE the PV MFMA so L2 writeback drains under compute.
  // Wave w owns rows {2w, 2w+1}; each pass one wave writes 2048B contiguous.
  {
    float s0 = 0.f, s1 = 0.f;
#pragma unroll
    for (int w = 0; w < 8; ++w) {
      s0 += wsum[w * 16 + wave * 2];
      s1 += wsum[w * 16 + wave * 2 + 1];
    }
    const float rw0 = 1.0f / s0, rw1 = 1.0f / s1;
    float* wbase = outW + ((size_t)(n * SEQ + row0)) * SEQ;
#pragma unroll
    for (int ps = 0; ps < 8; ++ps) {
      const int row = wave * 2 + (ps & 1);
      const float rs = (ps & 1) ? rw1 : rw0;
      const int cb8 = lane + ((ps >> 1) << 6);  // 16B-block index 0..255
      v8s pv = *(const v8s*)(smem + row * 4096 + ((cb8 ^ (row & 7)) << 4));
      v4f f0, f1;
      f0.x = bf2f(pv[0]) * rs; f0.y = bf2f(pv[1]) * rs;
      f0.z = bf2f(pv[2]) * rs; f0.w = bf2f(pv[3]) * rs;
      f1.x = bf2f(pv[4]) * rs; f1.y = bf2f(pv[5]) * rs;
      f1.z = bf2f(pv[6]) * rs; f1.w = bf2f(pv[7]) * rs;
      v4f* dst = (v4f*)(wbase + (size_t)row * SEQ + (cb8 << 3));
      dst[0] = f0;
      dst[1] = f1;
    }
  }

  // ---- Phase 3: O_partial = P(16x256) x V(256x64) via MFMA (LDS reads)
  v4f acc[4] = {{0.f,0.f,0.f,0.f},{0.f,0.f,0.f,0.f},{0.f,0.f,0.f,0.f},{0.f,0.f,0.f,0.f}};
#pragma unroll
  for (int ch = 0; ch < 8; ++ch) {
    const int cb = colw + ch * 32;
    v8s ap = *(const v8s*)(smem + lq * 4096 + (((((cb >> 3) + quad) ^ (lq & 7)) << 4)));
#pragma unroll
    for (int dt = 0; dt < 4; ++dt) {
      const unsigned short* vp =
          Vt + ((size_t)(n * DHEAD + dt * 16 + lq)) * SEQ + cb + quad * 8;
      v8s bp = *(const v8s*)vp;
      acc[dt] = __builtin_amdgcn_mfma_f32_16x16x32_bf16(ap, bp, acc[dt], 0, 0, 0);
    }
  }
  __syncthreads();  // all P reads (phase 2b + 3) done before olds overwrites

  // ---- Phase 4: cross-wave O reduction (8 partials of 16x64) through LDS;
  // rinv folded in before the store (per-row constant, distributes over sum).
  float* olds = (float*)smem;  // [8][16][68] padded
#pragma unroll
  for (int dt = 0; dt < 4; ++dt)
#pragma unroll
    for (int r = 0; r < 4; ++r)
      olds[wave * 1088 + (quad * 4 + r) * 68 + dt * 16 + lq] = acc[dt][r] * rinv[r];
  __syncthreads();
#pragma unroll
  for (int s = 0; s < 2; ++s) {
    int e = tid + s * 512;
    int row = e >> 6, d = e & 63;
    float a = 0.f;
#pragma unroll
    for (int w = 0; w < 8; ++w) a += olds[w * 1088 + row * 68 + d];
    outO[((size_t)(n * SEQ + row0 + row)) * DHEAD + d] = a;
  }
}

extern "C" void kernel_launch(void* const* d_in, const int* in_sizes, int n_in,
                              void* d_out, int out_size, void* d_ws, size_t ws_size,
                              hipStream_t stream) {
  const float* Q = (const float*)d_in[0];
  const float* K = (const float*)d_in[1];
  const float* V = (const float*)d_in[2];
  const int* kpm = (const int*)d_in[3];
  const int* am = (const int*)d_in[4];

  float* outO = (float*)d_out;
  float* outW = outO + (size_t)NBATCH * SEQ * DHEAD;  // 4,194,304 floats

  char* ws = (char*)d_ws;
  unsigned short* Qb = (unsigned short*)ws;                       // 8 MiB
  unsigned short* Kb = (unsigned short*)(ws + (8u << 20));        // 8 MiB
  unsigned short* Vt = (unsigned short*)(ws + (16u << 20));       // 8 MiB
  unsigned int* amB = (unsigned int*)(ws + (24u << 20));          // 512 KiB
  unsigned int* kpmB = (unsigned int*)(ws + (24u << 20) + (1u << 19));  // 8 KiB

  const int n4 = NBATCH * SEQ * DHEAD / 4;  // 1,048,576
  cvt_bf16_qk_k<<<dim3(n4 / 256, 2), 256, 0, stream>>>(Q, K, Qb, Kb, n4);
  vtrans_k<<<dim3(SEQ / 64, NBATCH), 256, 0, stream>>>(V, Vt);
  pack_amB_k<<<(SEQ * 64) / 256, 256, 0, stream>>>(am, amB);
  pack_kpm_k<<<8, 256, 0, stream>>>(kpm, kpmB);
  attn_main_k<<<NBATCH * (SEQ / 16), 512, 0, stream>>>(Qb, Kb, Vt, amB, kpmB,
                                                       outO, outW);
}

// Round 12
// 816.582 us; speedup vs baseline: 1.0150x; 1.0012x over previous
//
#include <hip/hip_runtime.h>
#include <stdint.h>

typedef __attribute__((ext_vector_type(8))) short v8s;
typedef __attribute__((ext_vector_type(4))) float v4f;

#define NBATCH 32
#define SEQ 2048
#define DHEAD 64

__device__ __forceinline__ unsigned short f2bf(float f) {
  unsigned int x = __float_as_uint(f);
  x += 0x7fffu + ((x >> 16) & 1u);
  return (unsigned short)(x >> 16);
}

__device__ __forceinline__ float bf2f(short s) {
  return __uint_as_float(((unsigned int)(unsigned short)s) << 16);
}

// ---- prepass: fp32 -> bf16 copy, Q and K in one launch (blockIdx.y picks) ----
// Q is PRE-SCALED by 0.125*log2(e): exp(S/8) = exp2((Q*0.18033688) . K).
__global__ void cvt_bf16_qk_k(const float* __restrict__ Q, const float* __restrict__ K,
                              unsigned short* __restrict__ Qb,
                              unsigned short* __restrict__ Kb, int n4) {
  int i = blockIdx.x * blockDim.x + threadIdx.x;
  if (i >= n4) return;
  const float* src = blockIdx.y ? K : Q;
  unsigned short* dst = blockIdx.y ? Kb : Qb;
  const float sc = blockIdx.y ? 1.0f : 0.18033688f;
  float4 v = ((const float4*)src)[i];
  ushort4 o;
  o.x = f2bf(v.x * sc); o.y = f2bf(v.y * sc);
  o.z = f2bf(v.z * sc); o.w = f2bf(v.w * sc);
  ((ushort4*)dst)[i] = o;
}

// ---- prepass: V (n,k,d) -> Vt (n,d,k) bf16 ----
__global__ void vtrans_k(const float* __restrict__ V,
                         unsigned short* __restrict__ Vt) {
  __shared__ float tile[64][65];
  int n = blockIdx.y, k0 = blockIdx.x * 64;
  int t = threadIdx.x;
  int c = t & 63, rb = t >> 6;
#pragma unroll
  for (int it = 0; it < 16; ++it) {
    int r = it * 4 + rb;
    tile[r][c] = V[((size_t)(n * SEQ + k0 + r)) * DHEAD + c];
  }
  __syncthreads();
#pragma unroll
  for (int it = 0; it < 16; ++it) {
    int d = it * 4 + rb;
    Vt[((size_t)(n * DHEAD + d)) * SEQ + k0 + c] = f2bf(tile[c][d]);
  }
}

// ---- prepass: attn_mask (m,k) int -> bits along k: amB[m][k/32] ----
__global__ void pack_amB_k(const int* __restrict__ am, unsigned int* __restrict__ amB) {
  int tid = blockIdx.x * blockDim.x + threadIdx.x;  // SEQ*64 = 131072 threads
  int w = tid & 63, m = tid >> 6;
  unsigned int bits = 0;
#pragma unroll 4
  for (int i = 0; i < 32; ++i)
    bits |= (am[(size_t)m * SEQ + w * 32 + i] != 0 ? 1u : 0u) << i;
  amB[m * 64 + w] = bits;
}

// ---- prepass: key_padding_mask (n,k) int -> bits kpmB[n][k/32] ----
__global__ void pack_kpm_k(const int* __restrict__ kpm, unsigned int* __restrict__ kpmB) {
  int tid = blockIdx.x * blockDim.x + threadIdx.x;  // 2048 threads
  if (tid >= NBATCH * 64) return;
  int n = tid >> 6, w = tid & 63;
  unsigned int bits = 0;
#pragma unroll 4
  for (int i = 0; i < 32; ++i)
    bits |= (kpm[n * SEQ + w * 32 + i] != 0 ? 1u : 0u) << i;
  kpmB[n * 64 + w] = bits;
}

// ---- main fused attention kernel ----
// R10/R11 diagnosis: MfmaUtil 3.8%, VALUBusy 23%, occ 44%, FETCH 24MB ->
// LATENCY-BOUND, MLP-starved (VGPR_Count=64 caps in-flight loads at ~2/wave).
// This version adds explicit MLP at the source level:
//  - phase 1: depth-4 ring prefetch of K fragments (8 loads in flight/wave)
//  - phase 3: next-chunk prefetch of 4 Vt fragments
//  - mask words hoisted out of the kt loop
// VGPR target ~110 (<128 keeps 2 blocks/CU; LDS is the binding limit).
// Layout/math identical to R11 (plain stores; unnormalized P; S^T mfma).
__global__ __launch_bounds__(512, 4)
void attn_main_k(const unsigned short* __restrict__ Qb,
                 const unsigned short* __restrict__ Kb,
                 const unsigned short* __restrict__ Vt,
                 const unsigned int* __restrict__ amB,
                 const unsigned int* __restrict__ kpmB,
                 float* __restrict__ outO, float* __restrict__ outW) {
  // [0,65536): P bf16, 16 rows x 4096 B, XOR-swizzled
  //   byte = row*4096 + ((col/8 ^ (row&7))*16) + (col&7)*2
  // [65536,66048): wsum[8][16] cross-wave row sums
  __shared__ __align__(16) char smem[66048];

  // XCD-aware swizzle (bijective on 0..4095; keeps 4 batches' K+Vt = 2MB/XCD)
  const int b = blockIdx.x;
  const int xcd = b & 7, slot = b >> 3;
  const int n = xcd + ((slot >> 7) << 3);
  const int row0 = (slot & 127) * 16;

  const int tid = threadIdx.x;
  const int wave = tid >> 6, lane = tid & 63;
  const int quad = lane >> 4, lq = lane & 15;
  const int colw = wave * 256;

  // Q B-fragments: Q[row0+lq][quad*8 + j] (+32 for second MFMA)
  const unsigned short* qp = Qb + ((size_t)(n * SEQ + row0 + lq)) * DHEAD + quad * 8;
  v8s a0 = *(const v8s*)qp;
  v8s a1 = *(const v8s*)(qp + 32);

  const unsigned int* amRow = amB + (size_t)(row0 + lq) * 64;
  const unsigned int* kpmRow = kpmB + n * 64 + (colw >> 5);

  // hoisted mask words: mwv[w2] covers key cols [colw + w2*32, +32)
  unsigned int mwv[8];
#pragma unroll
  for (int w2 = 0; w2 < 8; ++w2)
    mwv[w2] = amRow[(colw >> 5) + w2] | kpmRow[w2];

  // ---- Phase 1: S^T = (QK^T)^T, mask, exp -> unnormalized bf16 P to LDS
  // depth-4 ring prefetch of K fragments
  const unsigned short* kbase =
      Kb + ((size_t)(n * SEQ + colw + lq)) * DHEAD + quad * 8;
  v8s kb0[4], kb1[4];
#pragma unroll
  for (int i = 0; i < 4; ++i) {
    const unsigned short* kp = kbase + (size_t)(i * 16) * DHEAD;
    kb0[i] = *(const v8s*)kp;
    kb1[i] = *(const v8s*)(kp + 32);
  }

  float rsum = 0.f;
#pragma unroll
  for (int kt = 0; kt < 16; ++kt) {
    v8s b0 = kb0[kt & 3], b1 = kb1[kt & 3];
    if (kt < 12) {  // compile-time under full unroll; static ring index
      const unsigned short* kp = kbase + (size_t)((kt + 4) * 16) * DHEAD;
      kb0[kt & 3] = *(const v8s*)kp;
      kb1[kt & 3] = *(const v8s*)(kp + 32);
    }
    v4f c = {0.f, 0.f, 0.f, 0.f};
    c = __builtin_amdgcn_mfma_f32_16x16x32_bf16(b0, a0, c, 0, 0, 0);  // A=K, B=Q
    c = __builtin_amdgcn_mfma_f32_16x16x32_bf16(b1, a1, c, 0, 0, 0);
    const unsigned int mw = mwv[kt >> 1];
    const int bitbase = (kt & 1) * 16 + quad * 4;
    float e0, e1, e2, e3;
    e0 = (mw >> (bitbase + 0)) & 1u ? 0.f : exp2f(c[0]);
    e1 = (mw >> (bitbase + 1)) & 1u ? 0.f : exp2f(c[1]);
    e2 = (mw >> (bitbase + 2)) & 1u ? 0.f : exp2f(c[2]);
    e3 = (mw >> (bitbase + 3)) & 1u ? 0.f : exp2f(c[3]);
    rsum += (e0 + e1) + (e2 + e3);
    // pack 4 bf16 (4 consecutive key cols at row lq) -> one 8B LDS write
    uint2 dd;
    dd.x = ((unsigned int)f2bf(e0)) | (((unsigned int)f2bf(e1)) << 16);
    dd.y = ((unsigned int)f2bf(e2)) | (((unsigned int)f2bf(e3)) << 16);
    const int col0 = colw + kt * 16 + quad * 4;
    *(uint2*)(smem + lq * 4096 +
              ((((col0 >> 3) ^ (lq & 7)) << 4) | ((quad & 1) << 3))) = dd;
  }

  // ---- Row-sum reduce: all of lane's values belong to row lq -> quad reduce
  rsum += __shfl_xor(rsum, 16);
  rsum += __shfl_xor(rsum, 32);
  float* wsum = (float*)(smem + 65536);  // [8 waves][16 rows]
  if (quad == 0) wsum[wave * 16 + lq] = rsum;
  __syncthreads();  // P fully written + wsum visible

  // 1/rowsum for the rows this lane's PV accumulators own (quad*4+r)
  float rinv[4];
#pragma unroll
  for (int r = 0; r < 4; ++r) {
    float s = 0.f;
#pragma unroll
    for (int w = 0; w < 8; ++w) s += wsum[w * 16 + quad * 4 + r];
    rinv[r] = 1.0f / s;
  }

  // ---- Phase 2b: coalesced vectorized outW write from LDS, x (1/rowsum).
  // Issued BEFORE the PV MFMA so L2 writeback drains under compute.
  {
    float s0 = 0.f, s1 = 0.f;
#pragma unroll
    for (int w = 0; w < 8; ++w) {
      s0 += wsum[w * 16 + wave * 2];
      s1 += wsum[w * 16 + wave * 2 + 1];
    }
    const float rw0 = 1.0f / s0, rw1 = 1.0f / s1;
    float* wbase = outW + ((size_t)(n * SEQ + row0)) * SEQ;
#pragma unroll
    for (int ps = 0; ps < 8; ++ps) {
      const int row = wave * 2 + (ps & 1);
      const float rs = (ps & 1) ? rw1 : rw0;
      const int cb8 = lane + ((ps >> 1) << 6);  // 16B-block index 0..255
      v8s pv = *(const v8s*)(smem + row * 4096 + ((cb8 ^ (row & 7)) << 4));
      v4f f0, f1;
      f0.x = bf2f(pv[0]) * rs; f0.y = bf2f(pv[1]) * rs;
      f0.z = bf2f(pv[2]) * rs; f0.w = bf2f(pv[3]) * rs;
      f1.x = bf2f(pv[4]) * rs; f1.y = bf2f(pv[5]) * rs;
      f1.z = bf2f(pv[6]) * rs; f1.w = bf2f(pv[7]) * rs;
      v4f* dst = (v4f*)(wbase + (size_t)row * SEQ + (cb8 << 3));
      dst[0] = f0;
      dst[1] = f1;
    }
  }

  // ---- Phase 3: O_partial = P(16x256) x V(256x64) via MFMA (LDS reads),
  // with next-chunk prefetch of the 4 Vt fragments.
  const unsigned short* vtbase =
      Vt + ((size_t)(n * DHEAD + lq)) * SEQ + colw + quad * 8;
  v4f acc[4] = {{0.f,0.f,0.f,0.f},{0.f,0.f,0.f,0.f},{0.f,0.f,0.f,0.f},{0.f,0.f,0.f,0.f}};
  v8s vb[4];
#pragma unroll
  for (int dt = 0; dt < 4; ++dt)
    vb[dt] = *(const v8s*)(vtbase + (size_t)(dt * 16) * SEQ);
#pragma unroll
  for (int ch = 0; ch < 8; ++ch) {
    const int cb = colw + ch * 32;
    v8s ap = *(const v8s*)(smem + lq * 4096 + (((((cb >> 3) + quad) ^ (lq & 7)) << 4)));
#pragma unroll
    for (int dt = 0; dt < 4; ++dt) {
      v8s bp = vb[dt];
      if (ch < 7)  // compile-time under full unroll
        vb[dt] = *(const v8s*)(vtbase + (size_t)(dt * 16) * SEQ + (ch + 1) * 32);
      acc[dt] = __builtin_amdgcn_mfma_f32_16x16x32_bf16(ap, bp, acc[dt], 0, 0, 0);
    }
  }
  __syncthreads();  // all P reads (phase 2b + 3) done before olds overwrites

  // ---- Phase 4: cross-wave O reduction (8 partials of 16x64) through LDS;
  // rinv folded in before the store (per-row constant, distributes over sum).
  float* olds = (float*)smem;  // [8][16][68] padded
#pragma unroll
  for (int dt = 0; dt < 4; ++dt)
#pragma unroll
    for (int r = 0; r < 4; ++r)
      olds[wave * 1088 + (quad * 4 + r) * 68 + dt * 16 + lq] = acc[dt][r] * rinv[r];
  __syncthreads();
#pragma unroll
  for (int s = 0; s < 2; ++s) {
    int e = tid + s * 512;
    int row = e >> 6, d = e & 63;
    float a = 0.f;
#pragma unroll
    for (int w = 0; w < 8; ++w) a += olds[w * 1088 + row * 68 + d];
    outO[((size_t)(n * SEQ + row0 + row)) * DHEAD + d] = a;
  }
}

extern "C" void kernel_launch(void* const* d_in, const int* in_sizes, int n_in,
                              void* d_out, int out_size, void* d_ws, size_t ws_size,
                              hipStream_t stream) {
  const float* Q = (const float*)d_in[0];
  const float* K = (const float*)d_in[1];
  const float* V = (const float*)d_in[2];
  const int* kpm = (const int*)d_in[3];
  const int* am = (const int*)d_in[4];

  float* outO = (float*)d_out;
  float* outW = outO + (size_t)NBATCH * SEQ * DHEAD;  // 4,194,304 floats

  char* ws = (char*)d_ws;
  unsigned short* Qb = (unsigned short*)ws;                       // 8 MiB
  unsigned short* Kb = (unsigned short*)(ws + (8u << 20));        // 8 MiB
  unsigned short* Vt = (unsigned short*)(ws + (16u << 20));       // 8 MiB
  unsigned int* amB = (unsigned int*)(ws + (24u << 20));          // 512 KiB
  unsigned int* kpmB = (unsigned int*)(ws + (24u << 20) + (1u << 19));  // 8 KiB

  const int n4 = NBATCH * SEQ * DHEAD / 4;  // 1,048,576
  cvt_bf16_qk_k<<<dim3(n4 / 256, 2), 256, 0, stream>>>(Q, K, Qb, Kb, n4);
  vtrans_k<<<dim3(SEQ / 64, NBATCH), 256, 0, stream>>>(V, Vt);
  pack_amB_k<<<(SEQ * 64) / 256, 256, 0, stream>>>(am, amB);
  pack_kpm_k<<<8, 256, 0, stream>>>(kpm, kpmB);
  attn_main_k<<<NBATCH * (SEQ / 16), 512, 0, stream>>>(Qb, Kb, Vt, amB, kpmB,
                                                       outO, outW);
}